// Round 3
// baseline (81.211 us; speedup 1.0000x reference)
//
#include <hip/hip_runtime.h>

// RetinaNetFocalLoss on MI355X (gfx950).
// Inputs: clas_preds (16,49152,80) f32, bbox_preds (16,49152,4) f32,
//         bbox_tgts (16,64,4) f32 tlbr, clas_tgts (16,64) i32, anchors (49152,4) f32 cthw.
// Output: single f32 scalar.
//
// v3: 3-kernel split. (1) match: IoU argmax + huber + hot-class focal
// correction (per matched anchor), writes codes[] to ws. (2) focal: pure
// memory-bound streamer over clas_preds — all elements treated non-hot,
// masked 0/0.25 per anchor. (3) finalize: per-image divisors + mean.

#define A_CNT 49152
#define T_CNT 64
#define C_CNT 80
#define ABLK  256
#define NBLK  (A_CNT / ABLK)   // 192
#define B_CNT 16

// ---------- Kernel 1: matching + huber + hot focal correction ----------
__global__ __launch_bounds__(ABLK) void rnfl_match(
    const float* __restrict__ clas_preds,
    const float* __restrict__ bbox_preds,
    const float* __restrict__ bbox_tgts,
    const int*   __restrict__ clas_tgts,
    const float* __restrict__ anchors,
    int*   __restrict__ codes,      // [B_CNT*A_CNT]: -2 excl, -1 bkg, 0..79 hot
    float* __restrict__ bb_part,
    float* __restrict__ flh_part,
    int*   __restrict__ m_part)
{
    const int tid = threadIdx.x;
    const int b   = blockIdx.y;
    const int a0  = blockIdx.x * ABLK;

    __shared__ float4 tbox[T_CNT];
    __shared__ int    tcl[T_CNT];
    __shared__ float  rbb[4], rfl[4];
    __shared__ int    rmm[4];

    if (tid < T_CNT) {
        float4 bt = reinterpret_cast<const float4*>(bbox_tgts)[b * T_CNT + tid];
        // tlbr -> cthw -> tlbr (reference roundtrip)
        float cx = (bt.x + bt.z) * 0.5f;
        float cy = (bt.y + bt.w) * 0.5f;
        float sx = bt.z - bt.x;
        float sy = bt.w - bt.y;
        float4 tb;
        tb.x = cx - sx * 0.5f;
        tb.y = cy - sy * 0.5f;
        tb.z = cx + sx * 0.5f;
        tb.w = cy + sy * 0.5f;
        tbox[tid] = tb;
        tcl[tid]  = clas_tgts[b * T_CNT + tid];
    }
    __syncthreads();

    const int a = a0 + tid;
    float4 anc = reinterpret_cast<const float4*>(anchors)[a];
    const float ax1 = anc.x - anc.z * 0.5f;
    const float ay1 = anc.y - anc.w * 0.5f;
    const float ax2 = anc.x + anc.z * 0.5f;
    const float ay2 = anc.y + anc.w * 0.5f;
    const float areaA = anc.z * anc.w;

    float bn = -1.0f, bd = 1.0f;   // best IoU numerator / denominator
    int   bj = 0;
#pragma unroll 8
    for (int j = 0; j < T_CNT; ++j) {
        float4 tb = tbox[j];                 // wave-uniform b128 broadcast
        float ix1 = fmaxf(ax1, tb.x);
        float iy1 = fmaxf(ay1, tb.y);
        float ix2 = fminf(ax2, tb.z);
        float iy2 = fminf(ay2, tb.w);
        float w = fmaxf(ix2 - ix1, 0.0f);
        float h = fmaxf(iy2 - iy1, 0.0f);
        float inter = w * h;
        float den = areaA + (tb.z - tb.x) * (tb.w - tb.y) - inter + 1e-8f;
        if (inter * bd > bn * den) { bn = inter; bd = den; bj = j; }  // first-max
    }

    int   code;
    float bb   = 0.0f;
    float flh  = 0.0f;
    int   mloc = 0;
    if (bn > 0.5f * bd) {                    // iou > MATCH_THR
        mloc = 1;
        code = tcl[bj] - 1;                  // hot class in [0,79]
        float4 tb = tbox[bj];
        float gx = (tb.x + tb.z) * 0.5f;
        float gy = (tb.y + tb.w) * 0.5f;
        float gw = tb.z - tb.x;
        float gh = tb.w - tb.y;
        float4 bp = reinterpret_cast<const float4*>(bbox_preds)[(size_t)b * A_CNT + a];
        float t0 = ((gx - anc.x) / anc.z) * 10.0f;       // / SCALE 0.1
        float t1 = ((gy - anc.y) / anc.w) * 10.0f;
        float t2 = __logf(gw / anc.z + 1e-8f) * 5.0f;    // / SCALE 0.2
        float t3 = __logf(gh / anc.w + 1e-8f) * 5.0f;
        float d, ad;
        d = bp.x - t0; ad = fabsf(d); bb += (ad < 1.0f) ? 0.5f * d * d : ad - 0.5f;
        d = bp.y - t1; ad = fabsf(d); bb += (ad < 1.0f) ? 0.5f * d * d : ad - 0.5f;
        d = bp.z - t2; ad = fabsf(d); bb += (ad < 1.0f) ? 0.5f * d * d : ad - 0.5f;
        d = bp.w - t3; ad = fabsf(d); bb += (ad < 1.0f) ? 0.5f * d * d : ad - 0.5f;

        // hot focal correction: streamer adds 0.25*ps^2*sp for EVERY class;
        // replace the hot element's term with 0.75*(1-ps)^2*softplus(-x).
        float x = clas_preds[((size_t)b * A_CNT + a) * C_CNT + code];
        float e = __expf(x); float t = 1.0f + e;
        float inv = __builtin_amdgcn_rcpf(t);
        float ps = e * inv; float q = 1.0f - ps;
        float sp = __logf(t);
        flh = 0.75f * q * q * (sp - x) - 0.25f * ps * ps * sp;  // softplus(-x)=sp-x
    } else {
        code = (bn < 0.4f * bd) ? -1 : -2;
    }
    codes[(size_t)b * A_CNT + a] = code;     // coalesced

    // block reduction
#pragma unroll
    for (int off = 32; off > 0; off >>= 1) {
        bb   += __shfl_down(bb, off);
        flh  += __shfl_down(flh, off);
        mloc += __shfl_down(mloc, off);
    }
    const int wave = tid >> 6, lane = tid & 63;
    if (lane == 0) { rbb[wave] = bb; rfl[wave] = flh; rmm[wave] = mloc; }
    __syncthreads();
    if (tid == 0) {
        int slot = b * NBLK + blockIdx.x;
        bb_part[slot]  = rbb[0] + rbb[1] + rbb[2] + rbb[3];
        flh_part[slot] = rfl[0] + rfl[1] + rfl[2] + rfl[3];
        m_part[slot]   = rmm[0] + rmm[1] + rmm[2] + rmm[3];
    }
}

// ---------- Kernel 2: pure focal streamer ----------
__device__ __forceinline__ float focal_nh(float x) {
    // 0.25-scaled later: sigmoid(x)^2 * softplus(x), exp-form (|x| small)
    float e = __expf(x);
    float t = 1.0f + e;
    float inv = __builtin_amdgcn_rcpf(t);
    float ps = e * inv;
    float sp = __logf(t);
    return ps * ps * sp;
}

__global__ __launch_bounds__(ABLK) void rnfl_focal(
    const float* __restrict__ clas_preds,
    const int*   __restrict__ codes,
    float* __restrict__ fl_part)
{
    const int tid = threadIdx.x;
    const int b   = blockIdx.y;
    const int bx  = blockIdx.x;

    __shared__ int   lcode[ABLK];
    __shared__ float rfl[4];

    lcode[tid] = codes[(size_t)b * A_CNT + bx * ABLK + tid];
    __syncthreads();

    const float4* cp4 = reinterpret_cast<const float4*>(clas_preds)
                      + ((size_t)b * A_CNT + bx * ABLK) * (C_CNT / 4);

    float fl = 0.0f;
#pragma unroll 5
    for (int k = 0; k < 20; ++k) {
        int f  = k * ABLK + tid;             // float4 index within 256x80 slab
        int al = (unsigned)f / 20u;          // local anchor
        float4 v = cp4[f];
        float maskf = (lcode[al] >= -1) ? 0.25f : 0.0f;
        float s4 = focal_nh(v.x) + focal_nh(v.y) + focal_nh(v.z) + focal_nh(v.w);
        fl = fmaf(maskf, s4, fl);
    }

#pragma unroll
    for (int off = 32; off > 0; off >>= 1)
        fl += __shfl_down(fl, off);
    const int wave = tid >> 6, lane = tid & 63;
    if (lane == 0) rfl[wave] = fl;
    __syncthreads();
    if (tid == 0)
        fl_part[b * NBLK + bx] = rfl[0] + rfl[1] + rfl[2] + rfl[3];
}

// ---------- Kernel 3: finalize ----------
__global__ __launch_bounds__(256) void rnfl_final(
    const float* __restrict__ bb_part,
    const float* __restrict__ fl_part,
    const float* __restrict__ flh_part,
    const int*   __restrict__ m_part,
    float* __restrict__ out)
{
    const int tid = threadIdx.x, lane = tid & 63, wave = tid >> 6;
    __shared__ float wacc[4];
    float lacc = 0.0f;

    for (int img = wave; img < B_CNT; img += 4) {
        float bb = 0.0f, fl = 0.0f; int m = 0;
#pragma unroll
        for (int s = 0; s < 3; ++s) {        // 3*64 = 192 = NBLK
            int idx = img * NBLK + s * 64 + lane;
            bb += bb_part[idx];
            fl += fl_part[idx] + flh_part[idx];
            m  += m_part[idx];
        }
#pragma unroll
        for (int off = 32; off > 0; off >>= 1) {
            bb += __shfl_down(bb, off);
            fl += __shfl_down(fl, off);
            m  += __shfl_down(m, off);
        }
        if (lane == 0) {
            float mf = (float)m;
            lacc += bb / fmaxf(mf * 4.0f, 1.0f) + fl / fmaxf(mf, 1.0f);
        }
    }
    if (lane == 0) wacc[wave] = lacc;
    __syncthreads();
    if (tid == 0)
        out[0] = (wacc[0] + wacc[1] + wacc[2] + wacc[3]) / (float)B_CNT;
}

extern "C" void kernel_launch(void* const* d_in, const int* in_sizes, int n_in,
                              void* d_out, int out_size, void* d_ws, size_t ws_size,
                              hipStream_t stream)
{
    const float* clas_preds = (const float*)d_in[0];
    const float* bbox_preds = (const float*)d_in[1];
    const float* bbox_tgts  = (const float*)d_in[2];
    const int*   clas_tgts  = (const int*)d_in[3];
    const float* anchors    = (const float*)d_in[4];
    float* out = (float*)d_out;

    float* bb_part  = (float*)d_ws;                     // 3072
    float* fl_part  = bb_part + B_CNT * NBLK;           // 3072
    float* flh_part = fl_part + B_CNT * NBLK;           // 3072
    int*   m_part   = (int*)(flh_part + B_CNT * NBLK);  // 3072
    int*   codes    = m_part + B_CNT * NBLK;            // 786432

    dim3 grid(NBLK, B_CNT);
    rnfl_match<<<grid, ABLK, 0, stream>>>(clas_preds, bbox_preds, bbox_tgts,
                                          clas_tgts, anchors,
                                          codes, bb_part, flh_part, m_part);
    rnfl_focal<<<grid, ABLK, 0, stream>>>(clas_preds, codes, fl_part);
    rnfl_final<<<1, 256, 0, stream>>>(bb_part, fl_part, flh_part, m_part, out);
}

// Round 5
// 79.247 us; speedup vs baseline: 1.0248x; 1.0248x over previous
//
#include <hip/hip_runtime.h>

// RetinaNetFocalLoss on MI355X (gfx950).
// Inputs: clas_preds (16,49152,80) f32, bbox_preds (16,49152,4) f32,
//         bbox_tgts (16,64,4) f32 tlbr, clas_tgts (16,64) i32, anchors (49152,4) f32 cthw.
// Output: single f32 scalar.
//
// v5 (= v4 with compile fix): streamer rework — per-thread mask bits hoisted
// out of the hot loop, pure load+math loop (3 trans + ~5 VALU per element,
// log2-form with single final scale via __builtin_amdgcn_{exp2f,logf}),
// nontemporal float4 loads, 2 loads in flight per iteration.

#define A_CNT 49152
#define T_CNT 64
#define C_CNT 80
#define ABLK  256
#define NBLK  (A_CNT / ABLK)   // 192
#define B_CNT 16

typedef float f32x4 __attribute__((ext_vector_type(4)));

// ---------- Kernel 1: matching + huber + hot focal correction ----------
__global__ __launch_bounds__(ABLK) void rnfl_match(
    const float* __restrict__ clas_preds,
    const float* __restrict__ bbox_preds,
    const float* __restrict__ bbox_tgts,
    const int*   __restrict__ clas_tgts,
    const float* __restrict__ anchors,
    int*   __restrict__ codes,      // [B_CNT*A_CNT]: -2 excl, -1 bkg, 0..79 hot
    float* __restrict__ bb_part,
    float* __restrict__ flh_part,
    int*   __restrict__ m_part)
{
    const int tid = threadIdx.x;
    const int b   = blockIdx.y;
    const int a0  = blockIdx.x * ABLK;

    __shared__ float4 tbox[T_CNT];
    __shared__ int    tcl[T_CNT];
    __shared__ float  rbb[4], rfl[4];
    __shared__ int    rmm[4];

    if (tid < T_CNT) {
        float4 bt = reinterpret_cast<const float4*>(bbox_tgts)[b * T_CNT + tid];
        // tlbr -> cthw -> tlbr (reference roundtrip)
        float cx = (bt.x + bt.z) * 0.5f;
        float cy = (bt.y + bt.w) * 0.5f;
        float sx = bt.z - bt.x;
        float sy = bt.w - bt.y;
        float4 tb;
        tb.x = cx - sx * 0.5f;
        tb.y = cy - sy * 0.5f;
        tb.z = cx + sx * 0.5f;
        tb.w = cy + sy * 0.5f;
        tbox[tid] = tb;
        tcl[tid]  = clas_tgts[b * T_CNT + tid];
    }
    __syncthreads();

    const int a = a0 + tid;
    float4 anc = reinterpret_cast<const float4*>(anchors)[a];
    const float ax1 = anc.x - anc.z * 0.5f;
    const float ay1 = anc.y - anc.w * 0.5f;
    const float ax2 = anc.x + anc.z * 0.5f;
    const float ay2 = anc.y + anc.w * 0.5f;
    const float areaA = anc.z * anc.w;

    float bn = -1.0f, bd = 1.0f;   // best IoU numerator / denominator
    int   bj = 0;
#pragma unroll 8
    for (int j = 0; j < T_CNT; ++j) {
        float4 tb = tbox[j];                 // wave-uniform b128 broadcast
        float ix1 = fmaxf(ax1, tb.x);
        float iy1 = fmaxf(ay1, tb.y);
        float ix2 = fminf(ax2, tb.z);
        float iy2 = fminf(ay2, tb.w);
        float w = fmaxf(ix2 - ix1, 0.0f);
        float h = fmaxf(iy2 - iy1, 0.0f);
        float inter = w * h;
        float den = areaA + (tb.z - tb.x) * (tb.w - tb.y) - inter + 1e-8f;
        if (inter * bd > bn * den) { bn = inter; bd = den; bj = j; }  // first-max
    }

    int   code;
    float bb   = 0.0f;
    float flh  = 0.0f;
    int   mloc = 0;
    if (bn > 0.5f * bd) {                    // iou > MATCH_THR
        mloc = 1;
        code = tcl[bj] - 1;                  // hot class in [0,79]
        float4 tb = tbox[bj];
        float gx = (tb.x + tb.z) * 0.5f;
        float gy = (tb.y + tb.w) * 0.5f;
        float gw = tb.z - tb.x;
        float gh = tb.w - tb.y;
        float4 bp = reinterpret_cast<const float4*>(bbox_preds)[(size_t)b * A_CNT + a];
        float t0 = ((gx - anc.x) / anc.z) * 10.0f;       // / SCALE 0.1
        float t1 = ((gy - anc.y) / anc.w) * 10.0f;
        float t2 = __logf(gw / anc.z + 1e-8f) * 5.0f;    // / SCALE 0.2
        float t3 = __logf(gh / anc.w + 1e-8f) * 5.0f;
        float d, ad;
        d = bp.x - t0; ad = fabsf(d); bb += (ad < 1.0f) ? 0.5f * d * d : ad - 0.5f;
        d = bp.y - t1; ad = fabsf(d); bb += (ad < 1.0f) ? 0.5f * d * d : ad - 0.5f;
        d = bp.z - t2; ad = fabsf(d); bb += (ad < 1.0f) ? 0.5f * d * d : ad - 0.5f;
        d = bp.w - t3; ad = fabsf(d); bb += (ad < 1.0f) ? 0.5f * d * d : ad - 0.5f;

        // hot focal correction: streamer adds 0.25*ps^2*sp for EVERY class;
        // replace the hot element's term with 0.75*(1-ps)^2*softplus(-x).
        float x = clas_preds[((size_t)b * A_CNT + a) * C_CNT + code];
        float e = __expf(x); float t = 1.0f + e;
        float inv = __builtin_amdgcn_rcpf(t);
        float ps = e * inv; float q = 1.0f - ps;
        float sp = __logf(t);
        flh = 0.75f * q * q * (sp - x) - 0.25f * ps * ps * sp;  // softplus(-x)=sp-x
    } else {
        code = (bn < 0.4f * bd) ? -1 : -2;
    }
    codes[(size_t)b * A_CNT + a] = code;     // coalesced

    // block reduction
#pragma unroll
    for (int off = 32; off > 0; off >>= 1) {
        bb   += __shfl_down(bb, off);
        flh  += __shfl_down(flh, off);
        mloc += __shfl_down(mloc, off);
    }
    const int wave = tid >> 6, lane = tid & 63;
    if (lane == 0) { rbb[wave] = bb; rfl[wave] = flh; rmm[wave] = mloc; }
    __syncthreads();
    if (tid == 0) {
        int slot = b * NBLK + blockIdx.x;
        bb_part[slot]  = rbb[0] + rbb[1] + rbb[2] + rbb[3];
        flh_part[slot] = rfl[0] + rfl[1] + rfl[2] + rfl[3];
        m_part[slot]   = rmm[0] + rmm[1] + rmm[2] + rmm[3];
    }
}

// ---------- Kernel 2: pure focal streamer ----------
// Accumulates sigma(x)^2 * log2(1+e^x); scaled by 0.25*ln2 once at the end.
// v_exp_f32 is 2^x, v_log_f32 is log2(x) — use the raw builtins.
__device__ __forceinline__ float focal_l2(float x) {
    float e  = __builtin_amdgcn_exp2f(x * 1.44269504f);  // e^x
    float t  = 1.0f + e;
    float ps = e * __builtin_amdgcn_rcpf(t);             // sigmoid(x)
    float L  = __builtin_amdgcn_logf(t);                 // log2(1+e^x)
    return ps * ps * L;
}

__global__ __launch_bounds__(ABLK) void rnfl_focal(
    const float* __restrict__ clas_preds,
    const int*   __restrict__ codes,
    float* __restrict__ fl_part)
{
    const int tid = threadIdx.x;
    const int b   = blockIdx.y;
    const int bx  = blockIdx.x;

    __shared__ int   lcode[ABLK];
    __shared__ float rfl[4];

    lcode[tid] = codes[(size_t)b * A_CNT + bx * ABLK + tid];
    __syncthreads();

    // Hoist all mask logic: bit k = (anchor of float4 (k*ABLK+tid) included)
    unsigned mbits = 0;
#pragma unroll
    for (int k = 0; k < 20; ++k) {
        int al = (unsigned)(k * ABLK + tid) / 20u;
        mbits |= (lcode[al] >= -1 ? 1u : 0u) << k;
    }

    const f32x4* cp4 = reinterpret_cast<const f32x4*>(clas_preds)
                     + ((size_t)b * A_CNT + bx * ABLK) * (C_CNT / 4);

    float acc0 = 0.0f, acc1 = 0.0f;
#pragma unroll
    for (int k = 0; k < 20; k += 2) {
        f32x4 v0 = __builtin_nontemporal_load(cp4 + (k       * ABLK + tid));
        f32x4 v1 = __builtin_nontemporal_load(cp4 + ((k + 1) * ABLK + tid));
        float m0 = (float)((mbits >> k) & 1u);
        float m1 = (float)((mbits >> (k + 1)) & 1u);
        float s0 = ((focal_l2(v0.x) + focal_l2(v0.y))
                  + (focal_l2(v0.z) + focal_l2(v0.w)));
        float s1 = ((focal_l2(v1.x) + focal_l2(v1.y))
                  + (focal_l2(v1.z) + focal_l2(v1.w)));
        acc0 = fmaf(m0, s0, acc0);
        acc1 = fmaf(m1, s1, acc1);
    }
    float fl = (acc0 + acc1) * (0.25f * 0.6931471806f);   // *0.25*ln2

#pragma unroll
    for (int off = 32; off > 0; off >>= 1)
        fl += __shfl_down(fl, off);
    const int wave = tid >> 6, lane = tid & 63;
    if (lane == 0) rfl[wave] = fl;
    __syncthreads();
    if (tid == 0)
        fl_part[b * NBLK + bx] = rfl[0] + rfl[1] + rfl[2] + rfl[3];
}

// ---------- Kernel 3: finalize ----------
__global__ __launch_bounds__(256) void rnfl_final(
    const float* __restrict__ bb_part,
    const float* __restrict__ fl_part,
    const float* __restrict__ flh_part,
    const int*   __restrict__ m_part,
    float* __restrict__ out)
{
    const int tid = threadIdx.x, lane = tid & 63, wave = tid >> 6;
    __shared__ float wacc[4];
    float lacc = 0.0f;

    for (int img = wave; img < B_CNT; img += 4) {
        float bb = 0.0f, fl = 0.0f; int m = 0;
#pragma unroll
        for (int s = 0; s < 3; ++s) {        // 3*64 = 192 = NBLK
            int idx = img * NBLK + s * 64 + lane;
            bb += bb_part[idx];
            fl += fl_part[idx] + flh_part[idx];
            m  += m_part[idx];
        }
#pragma unroll
        for (int off = 32; off > 0; off >>= 1) {
            bb += __shfl_down(bb, off);
            fl += __shfl_down(fl, off);
            m  += __shfl_down(m, off);
        }
        if (lane == 0) {
            float mf = (float)m;
            lacc += bb / fmaxf(mf * 4.0f, 1.0f) + fl / fmaxf(mf, 1.0f);
        }
    }
    if (lane == 0) wacc[wave] = lacc;
    __syncthreads();
    if (tid == 0)
        out[0] = (wacc[0] + wacc[1] + wacc[2] + wacc[3]) / (float)B_CNT;
}

extern "C" void kernel_launch(void* const* d_in, const int* in_sizes, int n_in,
                              void* d_out, int out_size, void* d_ws, size_t ws_size,
                              hipStream_t stream)
{
    const float* clas_preds = (const float*)d_in[0];
    const float* bbox_preds = (const float*)d_in[1];
    const float* bbox_tgts  = (const float*)d_in[2];
    const int*   clas_tgts  = (const int*)d_in[3];
    const float* anchors    = (const float*)d_in[4];
    float* out = (float*)d_out;

    float* bb_part  = (float*)d_ws;                     // 3072
    float* fl_part  = bb_part + B_CNT * NBLK;           // 3072
    float* flh_part = fl_part + B_CNT * NBLK;           // 3072
    int*   m_part   = (int*)(flh_part + B_CNT * NBLK);  // 3072
    int*   codes    = m_part + B_CNT * NBLK;            // 786432

    dim3 grid(NBLK, B_CNT);
    rnfl_match<<<grid, ABLK, 0, stream>>>(clas_preds, bbox_preds, bbox_tgts,
                                          clas_tgts, anchors,
                                          codes, bb_part, flh_part, m_part);
    rnfl_focal<<<grid, ABLK, 0, stream>>>(clas_preds, codes, fl_part);
    rnfl_final<<<1, 256, 0, stream>>>(bb_part, fl_part, flh_part, m_part, out);
}